// Round 3
// baseline (81.664 us; speedup 1.0000x reference)
//
#include <hip/hip_runtime.h>

// GMM NLL loss: B=4, N=4096, M=4096, scalar output (mean nll).
// v4: single fused MFMA kernel, n un-split (each block owns ALL 4096 n for its
// 64-m tile), double-buffered LDS record chunks, inline log2+reduce+atomicAdd.
//
// Math (unchanged from v3, which passed): lp2[n][m] = vn . vm in log2 domain,
//   vn = [K2, A2, C2, Bx, By, Cz], vm = [1, txy2, tz2, tx, ty, tz].
// f32 split into bf16 hi+lo, 18 of 32 K-slots used:
//   A slots [nh0..5, nh0..5, nl0..5, 0..], B slots [mh0..5, ml0..5, mh0..5, 0..]
//   => nh*mh + nh*ml + nl*mh (drops nl*ml ~ 2^-18 rel).
//
// Grid (64 mtiles, 4 b) = 256 blocks = 1/CU exactly, no tail. 256 threads
// (4 waves x 16 m each). LDS = 2 x 512 records x 80 B = 80 KB double buffer;
// per chunk: build next chunk's records (2/thread) THEN 32 MFMA iterations,
// one barrier per chunk -> record-build latency hides under compute.

constexpr int Bc = 4, Nc = 4096, Mc = 4096;
constexpr int THREADS = 256;
constexpr int MBLK    = 64;            // m per block (16 per wave)
constexpr int NCK     = 512;           // n per LDS chunk
constexpr int NCHUNKS = Nc / NCK;      // 8
constexpr int CHT     = NCK / 16;      // 32 mfma tiles per chunk
constexpr int REC     = 40;            // shorts per n-record (80 B, 16B-aligned)

#define EPS 1e-8f
constexpr float LOG2E   = 1.4426950408889634f;
constexpr float LN2     = 0.6931471805599453f;
constexpr float LOG_2PI = 1.8378762043478343f;   // ln(2*3.14159), matches reference
constexpr float K_CONST = -1.5f * LOG_2PI * LOG2E;

typedef __attribute__((ext_vector_type(8))) short bf16x8;
typedef __attribute__((ext_vector_type(4))) float f32x4;
typedef unsigned int   u32;
typedef unsigned short u16;

static __device__ __forceinline__ u16 f2bf(float x) {    // RNE f32 -> bf16 bits
    u32 u = __float_as_uint(x);
    return (u16)((u + 0x7fffu + ((u >> 16) & 1u)) >> 16);
}
static __device__ __forceinline__ float bf2f(u16 h) {
    return __uint_as_float((u32)h << 16);
}

// Build NCK n-records (bf16 hi/lo, MFMA-A layout) into buf. 2 records/thread.
static __device__ __forceinline__ void build_records(
    short* __restrict__ buf,
    const float* __restrict__ pred_xyz,
    const float* __restrict__ pred_sigma,
    int b, int n0, int tid)
{
#pragma unroll
    for (int t = tid; t < NCK; t += THREADS) {
        const int n = n0 + t;
        const float* pp = pred_xyz + ((size_t)b * Nc + n) * 3;
        const float px = pp[0], py = pp[1], pz = pp[2];
        const float* ps = pred_sigma + ((size_t)b * Nc + n) * 2;
        const float sxy = ps[0] + EPS;
        const float sz  = ps[1] + EPS;
        const float A2 = -0.5f * LOG2E * __builtin_amdgcn_rcpf(sxy);
        const float C2 = -0.5f * LOG2E * __builtin_amdgcn_rcpf(sz);
        const float K2 = K_CONST - __builtin_amdgcn_logf(sxy)
                         - 0.5f * __builtin_amdgcn_logf(sz)
                         + A2 * (px * px + py * py) + C2 * (pz * pz);
        const float Bx = -2.f * A2 * px;
        const float By = -2.f * A2 * py;
        const float Cz = -2.f * C2 * pz;

        const u16 h0 = f2bf(K2), h1 = f2bf(A2), h2 = f2bf(C2),
                  h3 = f2bf(Bx), h4 = f2bf(By), h5 = f2bf(Cz);
        const u16 l0 = f2bf(K2 - bf2f(h0)), l1 = f2bf(A2 - bf2f(h1)),
                  l2 = f2bf(C2 - bf2f(h2)), l3 = f2bf(Bx - bf2f(h3)),
                  l4 = f2bf(By - bf2f(h4)), l5 = f2bf(Cz - bf2f(h5));

        const u32 d0 = (u32)h0 | ((u32)h1 << 16);
        const u32 d1 = (u32)h2 | ((u32)h3 << 16);
        const u32 d2 = (u32)h4 | ((u32)h5 << 16);
        const u32 e0 = (u32)l0 | ((u32)l1 << 16);
        const u32 e1 = (u32)l2 | ((u32)l3 << 16);
        const u32 e2 = (u32)l4 | ((u32)l5 << 16);
        u32* rec = (u32*)&buf[t * REC];
        rec[0] = d0; rec[1]  = d1; rec[2]  = d2;   // k0-5  : nh
        rec[3] = d0; rec[4]  = d1; rec[5]  = d2;   // k6-11 : nh
        rec[6] = e0; rec[7]  = e1; rec[8]  = e2;   // k12-17: nl
        rec[9] = 0;  rec[10] = 0;  rec[11] = 0;    // k18-31: must be 0
        rec[12] = 0; rec[13] = 0;  rec[14] = 0;  rec[15] = 0;
    }
}

__global__ __launch_bounds__(THREADS) void gmm_fused(
    const float* __restrict__ pred_xyz,   // (B,N,3)
    const float* __restrict__ pred_sigma, // (B,N,2)
    const float* __restrict__ target,     // (B,M,3)
    float* __restrict__ out)              // scalar, pre-zeroed by memset
{
    __shared__ short lds[2 * NCK * REC];  // 80 KB double buffer
    __shared__ float wsum[4];

    const int mblk = blockIdx.x;   // 0..63
    const int b    = blockIdx.y;   // 0..3
    const int tid  = threadIdx.x;
    const int lane = tid & 63;
    const int wave = tid >> 6;
    const int g    = lane >> 4;    // k-group

    // ---- B-fragment (m-side), fixed for whole kernel ----
    const int m = mblk * MBLK + wave * 16 + (lane & 15);
    const float* tp = target + ((size_t)b * Mc + m) * 3;
    const float tx = tp[0], ty = tp[1], tz = tp[2];
    const float u1 = tx * tx + ty * ty, u2 = tz * tz;

    const u16 mh0 = f2bf(1.f), mh1 = f2bf(u1), mh2 = f2bf(u2),
              mh3 = f2bf(tx),  mh4 = f2bf(ty), mh5 = f2bf(tz);
    const u16 ml0 = 0,
              ml1 = f2bf(u1 - bf2f(mh1)), ml2 = f2bf(u2 - bf2f(mh2)),
              ml3 = f2bf(tx - bf2f(mh3)), ml4 = f2bf(ty - bf2f(mh4)),
              ml5 = f2bf(tz - bf2f(mh5));

    u16 s0, s1, s2, s3, s4, s5, s6, s7;
    if (g == 0)      { s0=mh0; s1=mh1; s2=mh2; s3=mh3; s4=mh4; s5=mh5; s6=ml0; s7=ml1; }
    else if (g == 1) { s0=ml2; s1=ml3; s2=ml4; s3=ml5; s4=mh0; s5=mh1; s6=mh2; s7=mh3; }
    else if (g == 2) { s0=mh4; s1=mh5; s2=0;   s3=0;   s4=0;   s5=0;   s6=0;   s7=0;   }
    else             { s0=0;   s1=0;   s2=0;   s3=0;   s4=0;   s5=0;   s6=0;   s7=0;   }
    bf16x8 bfrag;
    bfrag[0]=(short)s0; bfrag[1]=(short)s1; bfrag[2]=(short)s2; bfrag[3]=(short)s3;
    bfrag[4]=(short)s4; bfrag[5]=(short)s5; bfrag[6]=(short)s6; bfrag[7]=(short)s7;

    // ---- prologue: chunk 0 into buf0 ----
    build_records(&lds[0], pred_xyz, pred_sigma, b, 0, tid);
    __syncthreads();

    // ---- main: per chunk, build next chunk (other buffer) then 32 MFMAs ----
    float a0 = 0.f, a1 = 0.f, a2 = 0.f, a3 = 0.f;
    const f32x4 zero4 = {0.f, 0.f, 0.f, 0.f};
    for (int ck = 0; ck < NCHUNKS; ++ck) {
        if (ck + 1 < NCHUNKS)
            build_records(&lds[((ck + 1) & 1) * (NCK * REC)],
                          pred_xyz, pred_sigma, b, (ck + 1) * NCK, tid);

        const short* base = &lds[(ck & 1) * (NCK * REC) + (lane & 15) * REC + g * 8];
#pragma unroll 4
        for (int it = 0; it < CHT; ++it) {
            bf16x8 afrag = *(const bf16x8*)(base + it * 16 * REC);
            f32x4 d = __builtin_amdgcn_mfma_f32_16x16x32_bf16(afrag, bfrag, zero4, 0, 0, 0);
            a0 += __builtin_amdgcn_exp2f(d[0]);
            a1 += __builtin_amdgcn_exp2f(d[1]);
            a2 += __builtin_amdgcn_exp2f(d[2]);
            a3 += __builtin_amdgcn_exp2f(d[3]);
        }
        __syncthreads();   // buf[ck&1] free for reuse; buf[(ck+1)&1] visible
    }

    // ---- inline finalize ----
    float s = (a0 + a1) + (a2 + a3);
    s += __shfl_xor(s, 16, 64);
    s += __shfl_xor(s, 32, 64);          // all lanes: full n-sum for their m
    float contrib = (lane < 16) ? __builtin_amdgcn_logf(s) : 0.f;  // log2(sum)
#pragma unroll
    for (int off = 32; off > 0; off >>= 1)
        contrib += __shfl_xor(contrib, off, 64);
    if (lane == 0) wsum[wave] = contrib;
    __syncthreads();
    if (tid == 0) {
        const float tot = wsum[0] + wsum[1] + wsum[2] + wsum[3];
        // nll_m = -ln2 * log2(sum_m); mean over B*M
        atomicAdd(out, -LN2 / (float)(Bc * Mc) * tot);
    }
}

extern "C" void kernel_launch(void* const* d_in, const int* in_sizes, int n_in,
                              void* d_out, int out_size, void* d_ws, size_t ws_size,
                              hipStream_t stream) {
    const float* pred_xyz   = (const float*)d_in[0];
    const float* pred_sigma = (const float*)d_in[1];
    const float* target     = (const float*)d_in[2];
    float* out = (float*)d_out;

    hipMemsetAsync(out, 0, sizeof(float), stream);   // race-free zero, capturable

    dim3 grid(Mc / MBLK, Bc, 1);   // (64, 4) = 256 blocks = 1/CU
    gmm_fused<<<grid, THREADS, 0, stream>>>(pred_xyz, pred_sigma, target, out);
}

// Round 4
// 70.498 us; speedup vs baseline: 1.1584x; 1.1584x over previous
//
#include <hip/hip_runtime.h>

// GMM NLL loss: B=4, N=4096, M=4096, scalar output (mean nll).
// v5: v3 structure (2 kernels, high occupancy) + 2 m-groups per wave.
// Math (passed in v3/v4): lp2[n][m] = vn . vm in log2 domain,
//   vn = [K2, A2, C2, Bx, By, Cz], vm = [1, txy2, tz2, tx, ty, tz].
// f32 split into bf16 hi+lo, 18 of 32 K-slots:
//   A slots [nh0..5, nh0..5, nl0..5, 0..], B slots [mh0..5, ml0..5, mh0..5, 0..]
//   => nh*mh + nh*ml + nl*mh (drops nl*ml ~ 2^-18 rel).
//
// v5 changes vs v3:
//  - MBLK 64 -> 128: each wave holds TWO B-fragments (32 m), so one
//    ds_read_b128 A-fragment feeds 2 MFMAs, and per-(b,nck) record build
//    redundancy halves (32 blocks instead of 64 rebuild the same chunk).
//  - grid (32, 8, 4) = 1024 blocks, 40 KB LDS -> 4 blocks/CU = 4 waves/SIMD.

constexpr int Bc = 4, Nc = 4096, Mc = 4096;
constexpr int NSPLIT  = 8;             // n split across blocks
constexpr int NCHUNK  = Nc / NSPLIT;   // 512 n per block
constexpr int NTILES  = NCHUNK / 16;   // 32 mfma iterations
constexpr int THREADS = 256;           // 4 waves
constexpr int MBLK    = 128;           // 128 m per block (32 per wave)
constexpr int REC     = 40;            // shorts per n-record (80 B, 16B-aligned)

#define EPS 1e-8f
constexpr float LOG2E   = 1.4426950408889634f;
constexpr float LN2     = 0.6931471805599453f;
constexpr float LOG_2PI = 1.8378762043478343f;   // ln(2*3.14159), matches reference
constexpr float K_CONST = -1.5f * LOG_2PI * LOG2E;

typedef __attribute__((ext_vector_type(8))) short bf16x8;
typedef __attribute__((ext_vector_type(4))) float f32x4;
typedef unsigned int   u32;
typedef unsigned short u16;

static __device__ __forceinline__ u16 f2bf(float x) {    // RNE f32 -> bf16 bits
    u32 u = __float_as_uint(x);
    return (u16)((u + 0x7fffu + ((u >> 16) & 1u)) >> 16);
}
static __device__ __forceinline__ float bf2f(u16 h) {
    return __uint_as_float((u32)h << 16);
}

// Build one B-fragment for target index m (k-group g = lane>>4).
static __device__ __forceinline__ bf16x8 make_bfrag(
    const float* __restrict__ target, int b, int m, int g)
{
    const float* tp = target + ((size_t)b * Mc + m) * 3;
    const float tx = tp[0], ty = tp[1], tz = tp[2];
    const float u1 = tx * tx + ty * ty, u2 = tz * tz;

    const u16 mh0 = f2bf(1.f), mh1 = f2bf(u1), mh2 = f2bf(u2),
              mh3 = f2bf(tx),  mh4 = f2bf(ty), mh5 = f2bf(tz);
    const u16 ml0 = 0,
              ml1 = f2bf(u1 - bf2f(mh1)), ml2 = f2bf(u2 - bf2f(mh2)),
              ml3 = f2bf(tx - bf2f(mh3)), ml4 = f2bf(ty - bf2f(mh4)),
              ml5 = f2bf(tz - bf2f(mh5));

    u16 s0, s1, s2, s3, s4, s5, s6, s7;
    if (g == 0)      { s0=mh0; s1=mh1; s2=mh2; s3=mh3; s4=mh4; s5=mh5; s6=ml0; s7=ml1; }
    else if (g == 1) { s0=ml2; s1=ml3; s2=ml4; s3=ml5; s4=mh0; s5=mh1; s6=mh2; s7=mh3; }
    else if (g == 2) { s0=mh4; s1=mh5; s2=0;   s3=0;   s4=0;   s5=0;   s6=0;   s7=0;   }
    else             { s0=0;   s1=0;   s2=0;   s3=0;   s4=0;   s5=0;   s6=0;   s7=0;   }
    bf16x8 f;
    f[0]=(short)s0; f[1]=(short)s1; f[2]=(short)s2; f[3]=(short)s3;
    f[4]=(short)s4; f[5]=(short)s5; f[6]=(short)s6; f[7]=(short)s7;
    return f;
}

__global__ __launch_bounds__(THREADS) void gmm_partial(
    const float* __restrict__ pred_xyz,   // (B,N,3)
    const float* __restrict__ pred_sigma, // (B,N,2)
    const float* __restrict__ target,     // (B,M,3)
    float* __restrict__ partials,         // (B, NSPLIT, M)
    float* __restrict__ out)
{
    __shared__ short lds[NCHUNK * REC];   // 40 KB -> 4 blocks/CU

    const int mblk = blockIdx.x;   // 0..31  (m tile of 128)
    const int nck  = blockIdx.y;   // 0..7   (n chunk)
    const int b    = blockIdx.z;
    const int tid  = threadIdx.x;

    if (mblk == 0 && nck == 0 && b == 0 && tid == 0) out[0] = 0.f;

    // ---- phase 1: n-coefs -> bf16 hi/lo records in LDS (2 n per thread) ----
#pragma unroll
    for (int t = tid; t < NCHUNK; t += THREADS) {
        const int n = nck * NCHUNK + t;
        const float* pp = pred_xyz + ((size_t)b * Nc + n) * 3;
        const float px = pp[0], py = pp[1], pz = pp[2];
        const float* ps = pred_sigma + ((size_t)b * Nc + n) * 2;
        const float sxy = ps[0] + EPS;
        const float sz  = ps[1] + EPS;
        const float A2 = -0.5f * LOG2E * __builtin_amdgcn_rcpf(sxy);
        const float C2 = -0.5f * LOG2E * __builtin_amdgcn_rcpf(sz);
        const float K2 = K_CONST - __builtin_amdgcn_logf(sxy)
                         - 0.5f * __builtin_amdgcn_logf(sz)
                         + A2 * (px * px + py * py) + C2 * (pz * pz);
        const float Bx = -2.f * A2 * px;
        const float By = -2.f * A2 * py;
        const float Cz = -2.f * C2 * pz;

        const u16 h0 = f2bf(K2), h1 = f2bf(A2), h2 = f2bf(C2),
                  h3 = f2bf(Bx), h4 = f2bf(By), h5 = f2bf(Cz);
        const u16 l0 = f2bf(K2 - bf2f(h0)), l1 = f2bf(A2 - bf2f(h1)),
                  l2 = f2bf(C2 - bf2f(h2)), l3 = f2bf(Bx - bf2f(h3)),
                  l4 = f2bf(By - bf2f(h4)), l5 = f2bf(Cz - bf2f(h5));

        const u32 d0 = (u32)h0 | ((u32)h1 << 16);
        const u32 d1 = (u32)h2 | ((u32)h3 << 16);
        const u32 d2 = (u32)h4 | ((u32)h5 << 16);
        const u32 e0 = (u32)l0 | ((u32)l1 << 16);
        const u32 e1 = (u32)l2 | ((u32)l3 << 16);
        const u32 e2 = (u32)l4 | ((u32)l5 << 16);
        u32* rec = (u32*)&lds[t * REC];
        rec[0] = d0; rec[1]  = d1; rec[2]  = d2;   // k0-5  : nh
        rec[3] = d0; rec[4]  = d1; rec[5]  = d2;   // k6-11 : nh
        rec[6] = e0; rec[7]  = e1; rec[8]  = e2;   // k12-17: nl
        rec[9] = 0;  rec[10] = 0;  rec[11] = 0;    // k18-31: must be 0
        rec[12] = 0; rec[13] = 0;  rec[14] = 0;  rec[15] = 0;
    }
    __syncthreads();

    // ---- B-fragments: 2 m-groups per wave (32 m), fixed for whole kernel ----
    const int lane = tid & 63;
    const int wave = tid >> 6;
    const int g    = lane >> 4;           // k-group
    const int mA   = mblk * MBLK + wave * 32 + (lane & 15);
    const int mB   = mA + 16;

    const bf16x8 bfragA = make_bfrag(target, b, mA, g);
    const bf16x8 bfragB = make_bfrag(target, b, mB, g);

    // ---- main loop: 1 ds_read_b128 feeds 2 MFMAs; 8 exp2 + 8 add per 16 n ----
    float aA0 = 0.f, aA1 = 0.f, aA2 = 0.f, aA3 = 0.f;
    float aB0 = 0.f, aB1 = 0.f, aB2 = 0.f, aB3 = 0.f;
    const short* abase = &lds[(lane & 15) * REC + g * 8];
    const f32x4 zero4 = {0.f, 0.f, 0.f, 0.f};
#pragma unroll 4
    for (int it = 0; it < NTILES; ++it) {
        bf16x8 afrag = *(const bf16x8*)(abase + it * 16 * REC);
        f32x4 dA = __builtin_amdgcn_mfma_f32_16x16x32_bf16(afrag, bfragA, zero4, 0, 0, 0);
        f32x4 dB = __builtin_amdgcn_mfma_f32_16x16x32_bf16(afrag, bfragB, zero4, 0, 0, 0);
        aA0 += __builtin_amdgcn_exp2f(dA[0]);
        aA1 += __builtin_amdgcn_exp2f(dA[1]);
        aA2 += __builtin_amdgcn_exp2f(dA[2]);
        aA3 += __builtin_amdgcn_exp2f(dA[3]);
        aB0 += __builtin_amdgcn_exp2f(dB[0]);
        aB1 += __builtin_amdgcn_exp2f(dB[1]);
        aB2 += __builtin_amdgcn_exp2f(dB[2]);
        aB3 += __builtin_amdgcn_exp2f(dB[3]);
    }

    float sA = (aA0 + aA1) + (aA2 + aA3);
    sA += __shfl_xor(sA, 16, 64);
    sA += __shfl_xor(sA, 32, 64);
    float sB = (aB0 + aB1) + (aB2 + aB3);
    sB += __shfl_xor(sB, 16, 64);
    sB += __shfl_xor(sB, 32, 64);
    if (g == 0) {
        float* dst = partials + ((size_t)(b * NSPLIT + nck)) * Mc;
        dst[mA] = sA;
        dst[mB] = sB;
    }
}

// Finalize: 64 blocks x 256 threads; thread t -> (b,m). Sum NSPLIT chunks,
// log2, wave+block reduce, one atomicAdd per block.
__global__ __launch_bounds__(256) void gmm_finalize(
    const float* __restrict__ partials, float* __restrict__ out)
{
    const int t = blockIdx.x * 256 + threadIdx.x;
    const int b = t >> 12;
    const int m = t & (Mc - 1);

    float sum = 0.f;
#pragma unroll
    for (int c = 0; c < NSPLIT; ++c)
        sum += partials[((size_t)(b * NSPLIT + c)) * Mc + m];

    float local = __builtin_amdgcn_logf(sum);   // log2(sum)
#pragma unroll
    for (int off = 32; off > 0; off >>= 1)
        local += __shfl_down(local, off, 64);

    __shared__ float w[4];
    const int wave = threadIdx.x >> 6;
    if ((threadIdx.x & 63) == 0) w[wave] = local;
    __syncthreads();
    if (threadIdx.x == 0) {
        const float tot = w[0] + w[1] + w[2] + w[3];
        atomicAdd(out, -LN2 / (float)(Bc * Mc) * tot);
    }
}

extern "C" void kernel_launch(void* const* d_in, const int* in_sizes, int n_in,
                              void* d_out, int out_size, void* d_ws, size_t ws_size,
                              hipStream_t stream) {
    const float* pred_xyz   = (const float*)d_in[0];
    const float* pred_sigma = (const float*)d_in[1];
    const float* target     = (const float*)d_in[2];
    float* out      = (float*)d_out;
    float* partials = (float*)d_ws;   // B*NSPLIT*M floats = 512 KB

    dim3 grid(Mc / MBLK, NSPLIT, Bc);   // (32, 8, 4) = 1024 blocks
    gmm_partial<<<grid, THREADS, 0, stream>>>(pred_xyz, pred_sigma, target,
                                              partials, out);
    gmm_finalize<<<Bc * Mc / 256, 256, 0, stream>>>(partials, out);
}